// Round 2
// 669.202 us; speedup vs baseline: 1.1107x; 1.1107x over previous
//
#include <hip/hip_runtime.h>
#include <math.h>

#define BB  32
#define CC  80
#define TXX 512
#define TYY 2048
#define NEGV -1e9f

typedef float v2f __attribute__((ext_vector_type(2)));

// ---------------- prep: o_scale tables, per-t terms, f32 transposed copies ----------------
__global__ __launch_bounds__(256) void k_prep(
    const float* __restrict__ om, const float* __restrict__ ols,
    float* __restrict__ SA, float* __restrict__ SB,
    float* __restrict__ L1, float* __restrict__ L4,
    float* __restrict__ OMTf, float* __restrict__ OLSTf)
{
    int b = blockIdx.y;
    int t0 = blockIdx.x * 64;
    int tid = threadIdx.x;
    int cl = tid >> 6;          // 0..3
    int tl = tid & 63;
    __shared__ float sm[64][81], sl[64][81], ssa[64][81];
    #pragma unroll
    for (int cp = 0; cp < 20; ++cp) {
        int c = cp * 4 + cl;
        size_t gidx = ((size_t)b * CC + c) * TXX + t0 + tl;
        float m = om[gidx], ls = ols[gidx];
        float sa = expf(-2.0f * ls);
        SA[gidx] = sa;
        SB[gidx] = m * sa;
        sm[tl][c] = m; sl[tl][c] = ls; ssa[tl][c] = sa;
    }
    __syncthreads();
    if (tid < 64) {
        float l1 = 0.f, l4 = 0.f;
        #pragma unroll 4
        for (int c = 0; c < CC; ++c) {
            float m = sm[tid][c], ls = sl[tid][c], sa = ssa[tid][c];
            l1 += (-0.9189385332046727f - ls);
            l4 += ((-0.5f * m) * m) * sa;
        }
        int g = b * TXX + t0 + tid;
        L1[g] = l1; L4[g] = l4;
    }
    size_t obase = (size_t)b * TXX * CC + (size_t)t0 * CC;
    for (int e = tid; e < 64 * CC; e += 256) {
        int t = e / CC, c = e - t * CC;
        OMTf[obase + e]  = sm[t][c];
        OLSTf[obase + e] = sl[t][c];
    }
}

// ---------------- logp GEMM: [Tx,K=80]x[K,Ty] per batch, packed-f32 vector ----------------
__global__ __launch_bounds__(256) void k_logp(
    const float* __restrict__ SA, const float* __restrict__ SB,
    const float* __restrict__ L1, const float* __restrict__ L4,
    const float* __restrict__ z,
    const int* __restrict__ xlp, const int* __restrict__ ylp,
    float* __restrict__ logp)
{
    int b = blockIdx.z;
    int ylen = (ylp[b] >> 1) << 1;
    int s0 = blockIdx.y * 128;
    if (s0 >= ylen) return;            // DP never reads rows >= ylen; k_attn overwrites later
    int t0 = blockIdx.x * 64;
    int xlen = xlp[b];
    int tid = threadIdx.x;

    __shared__ float sA[16][64], sB[16][64], sZ[16][128], sW[16][128];

    v2f acc2[4][4], acc3[4][4];
    #pragma unroll
    for (int i = 0; i < 4; ++i)
        #pragma unroll
        for (int p = 0; p < 4; ++p) { acc2[i][p] = (v2f){0.f, 0.f}; acc3[i][p] = (v2f){0.f, 0.f}; }

    int tt = (tid & 15) << 2;
    int ss = (tid >> 4) << 3;
    int r  = tid >> 4;
    int c4 = (tid & 15) << 2;
    int s8 = (tid & 15) << 3;

    for (int c0 = 0; c0 < CC; c0 += 16) {
        const float* pa = SA + ((size_t)b * CC + (c0 + r)) * TXX + t0 + c4;
        const float* pb = SB + ((size_t)b * CC + (c0 + r)) * TXX + t0 + c4;
        float4 va = *(const float4*)pa;
        float4 vb = *(const float4*)pb;
        *(float4*)&sA[r][c4] = va;
        *(float4*)&sB[r][c4] = vb;

        const float* pz = z + ((size_t)b * CC + (c0 + r)) * TYY + s0 + s8;
        float4 q0 = *(const float4*)pz;
        float4 q1 = *(const float4*)(pz + 4);
        float zf[8] = {q0.x, q0.y, q0.z, q0.w, q1.x, q1.y, q1.z, q1.w};
        #pragma unroll
        for (int i = 0; i < 8; ++i) {
            sZ[r][s8 + i] = zf[i];
            sW[r][s8 + i] = (-0.5f * zf[i]) * zf[i];
        }
        __syncthreads();
        #pragma unroll
        for (int kc = 0; kc < 16; ++kc) {
            float4 a2 = *(const float4*)&sA[kc][tt];
            float4 a3 = *(const float4*)&sB[kc][tt];
            const v2f* zp = (const v2f*)&sZ[kc][ss];
            const v2f* wp = (const v2f*)&sW[kc][ss];
            v2f bz[4] = {zp[0], zp[1], zp[2], zp[3]};
            v2f bw[4] = {wp[0], wp[1], wp[2], wp[3]};
            float av2[4] = {a2.x, a2.y, a2.z, a2.w};
            float av3[4] = {a3.x, a3.y, a3.z, a3.w};
            #pragma unroll
            for (int i = 0; i < 4; ++i) {
                v2f d2 = {av2[i], av2[i]};
                v2f d3 = {av3[i], av3[i]};
                #pragma unroll
                for (int p = 0; p < 4; ++p) {
                    acc2[i][p] = __builtin_elementwise_fma(d2, bw[p], acc2[i][p]);
                    acc3[i][p] = __builtin_elementwise_fma(d3, bz[p], acc3[i][p]);
                }
            }
        }
        __syncthreads();
    }

    float l1a[4], l4a[4]; int bad[4];
    #pragma unroll
    for (int i = 0; i < 4; ++i) {
        int t = t0 + tt + i;
        l1a[i] = L1[b * TXX + t];
        l4a[i] = L4[b * TXX + t];
        bad[i] = (t >= xlen);
    }
    #pragma unroll
    for (int p = 0; p < 4; ++p) {
        #pragma unroll
        for (int h = 0; h < 2; ++h) {
            int s = s0 + ss + 2 * p + h;
            float vals[4];
            #pragma unroll
            for (int i = 0; i < 4; ++i) {
                float a2v = h ? acc2[i][p].y : acc2[i][p].x;
                float a3v = h ? acc3[i][p].y : acc3[i][p].x;
                float v = ((l1a[i] + a2v) + a3v) + l4a[i];
                vals[i] = bad[i] ? NEGV : v;
            }
            float4 o; o.x = vals[0]; o.y = vals[1]; o.z = vals[2]; o.w = vals[3];
            *(float4*)&logp[((size_t)b * TYY + s) * TXX + t0 + tt] = o;
        }
    }
}

// ---------------- forward Viterbi DP: skewed 8-wave pipeline, 1 col per lane ----------------
// Round r: wave w runs s-block blk=r-w (64 steps). Boundary v[64w-1] flows
// wave(w-1)->wave(w) via per-round register latch + 1 LDS ring write/read.
// Step body is branch-free -> full unroll, c[16] stays in VGPRs (round 6 spilled).
__global__ __launch_bounds__(512) void k_fwd(
    const float* __restrict__ logp, const int* __restrict__ ylp,
    unsigned long long* __restrict__ BITS64)   // [b][8][2048]
{
    int b = blockIdx.x;
    int tid = threadIdx.x;
    int w = tid >> 6, lane = tid & 63;
    int n = (ylp[b] >> 1) << 1;          // 1024..2048, even
    int nm1 = n - 1;
    int nb = (n + 63) >> 6;
    const float* lpt = logp + (size_t)b * TYY * TXX + tid;   // column t=tid
    unsigned long long* bout = BITS64 + ((size_t)b * 8 + w) * TYY;

    __shared__ float bnd[8][4][64];      // [wave][ring][step-in-block] latch of v63

    float v = (tid == 0) ? 0.0f : NEGV;
    float c[16];
    unsigned blo = 0u, bhi = 0u;
    int rounds = nb + 7;
    for (int r = 0; r < rounds; ++r) {
        int blk = r - w;
        if (blk >= 0 && blk < nb) {
            int S0 = blk << 6;
            if (blk == 0) {              // fill prefetch pipe (rows 0..15 valid: n>=1024)
                #pragma unroll
                for (int i = 0; i < 16; ++i) c[i] = lpt[(size_t)i * TXX];
            }
            // BL[lane] = v63 after step S0-1+lane (from wave w-1's latches)
            float BL;
            if (w == 0) {
                BL = NEGV;
            } else {
                const float* srcp = (lane == 0) ? &bnd[w - 1][(blk + 3) & 3][63]
                                                : &bnd[w - 1][blk & 3][lane - 1];
                BL = *srcp;
                if (blk == 0 && lane == 0) BL = NEGV;   // step -1 boundary
            }
            float BLout = 0.0f;
            #pragma unroll
            for (int j = 0; j < 64; ++j) {
                float cc = c[j & 15];
                int ps = S0 + j + 16; ps = (ps > nm1) ? nm1 : ps;   // scalar clamp, no branch
                c[j & 15] = lpt[(size_t)ps * TXX];
                float left = __shfl_up(v, 1, 64);
                float blj = __uint_as_float(
                    __builtin_amdgcn_readlane(__float_as_uint(BL), j));
                if (lane == 0) left = blj;
                unsigned long long m = __ballot(v < left);   // bits of row S0+j-1
                bool me = (lane == j);
                blo = me ? (unsigned)m : blo;
                bhi = me ? (unsigned)(m >> 32) : bhi;
                v = cc + fmaxf(v, left);
                float v63 = __uint_as_float(
                    __builtin_amdgcn_readlane(__float_as_uint(v), 63));
                BLout = me ? v63 : BLout;
            }
            bnd[w][blk & 3][lane] = BLout;
            int row = S0 - 1 + lane;
            if (row >= 0 && S0 + lane < n)
                bout[row] = (((unsigned long long)bhi) << 32) | blo;
        }
        __syncthreads();
    }
}

// ---------------- backtrack: wave-uniform SALU chain over u64 bit planes ----------------
// All 64 lanes share the same idx chain (wave-uniform) -> broadcast via v_readlane
// (compile-time lane index, no LDS on the critical path); decision arithmetic stays
// in uniform scalar ops. 64-step chunks; each lane holds one row's 128-bit window
// (2 coalesced u64 loads per chunk). tstar captured via per-lane cndmask side chain.
// No atomics: DUR is recovered in k_small by binary search over monotone TSTAR.
__global__ __launch_bounds__(64) void k_bwd(
    const unsigned long long* __restrict__ BITS64, const int* __restrict__ xlp,
    const int* __restrict__ ylp, int* __restrict__ TSTAR)
{
    int b = blockIdx.x, lane = threadIdx.x;
    int ylen = (ylp[b] >> 1) << 1;       // >= 1024, even
    int xlen = xlp[b];
    const unsigned long long* bb = BITS64 + (size_t)b * 8 * TYY;
    int* tst = TSTAR + b * TYY;

    int idx = xlen - 1;                  // wave-uniform
    int j_hi = ylen - 1;

    // full 64-step chunks
    while (j_hi >= 63) {
        int e = idx >> 6;
        int base_w = (e > 0) ? (e - 1) : 0;      // window planes {base_w, base_w+1}, base_w<=6
        int base_bit = base_w << 6;              // pos = idx-base_bit in [0,127], stays >=0
        int row = j_hi - 1 - lane;               // row consumed at step k==lane
        unsigned long long wl = 0ull, wh = 0ull;
        if (row >= 0) {
            wl = bb[(size_t)base_w * TYY + row];
            wh = bb[(size_t)(base_w + 1) * TYY + row];
        }
        unsigned wl0 = (unsigned)wl, wl1 = (unsigned)(wl >> 32);
        unsigned wh0 = (unsigned)wh, wh1 = (unsigned)(wh >> 32);
        int acc = 0;
        int pos = idx - base_bit;
        #pragma unroll
        for (int k = 0; k < 64; ++k) {
            int j = j_hi - k;
            unsigned a0 = __builtin_amdgcn_readlane(wl0, k);   // off the idx chain
            unsigned a1 = __builtin_amdgcn_readlane(wl1, k);
            unsigned c0 = __builtin_amdgcn_readlane(wh0, k);
            unsigned c1 = __builtin_amdgcn_readlane(wh1, k);
            unsigned long long wkl = ((unsigned long long)a1 << 32) | a0;
            unsigned long long wkh = ((unsigned long long)c1 << 32) | c0;
            unsigned long long sel = (pos & 64) ? wkh : wkl;
            unsigned bit = (unsigned)(sel >> (pos & 63)) & 1u;
            int idxv = pos + base_bit;
            acc = (lane == k) ? idxv : acc;                    // tstar[j] side chain
            int dec = (idxv != 0 && j > 0 && (idxv == j || bit)) ? 1 : 0;
            pos -= dec;
        }
        idx = pos + base_bit;
        tst[j_hi - lane] = acc;                  // lane k holds tstar[j_hi-k]
        j_hi -= 64;
    }
    // tail chunk (<= 63 steps)
    if (j_hi >= 0) {
        int steps = j_hi + 1;
        int e = idx >> 6;
        int base_w = (e > 0) ? (e - 1) : 0;
        int base_bit = base_w << 6;
        int row = j_hi - 1 - lane;
        unsigned long long wl = 0ull, wh = 0ull;
        if (row >= 0) {
            wl = bb[(size_t)base_w * TYY + row];
            wh = bb[(size_t)(base_w + 1) * TYY + row];
        }
        unsigned wl0 = (unsigned)wl, wl1 = (unsigned)(wl >> 32);
        unsigned wh0 = (unsigned)wh, wh1 = (unsigned)(wh >> 32);
        int acc = 0;
        int pos = idx - base_bit;
        for (int k = 0; k < steps; ++k) {
            int j = j_hi - k;
            unsigned a0 = __builtin_amdgcn_readlane(wl0, k);
            unsigned a1 = __builtin_amdgcn_readlane(wl1, k);
            unsigned c0 = __builtin_amdgcn_readlane(wh0, k);
            unsigned c1 = __builtin_amdgcn_readlane(wh1, k);
            unsigned long long wkl = ((unsigned long long)a1 << 32) | a0;
            unsigned long long wkh = ((unsigned long long)c1 << 32) | c0;
            unsigned long long sel = (pos & 64) ? wkh : wkl;
            unsigned bit = (unsigned)(sel >> (pos & 63)) & 1u;
            int idxv = pos + base_bit;
            acc = (lane == k) ? idxv : acc;
            int dec = (idxv != 0 && j > 0 && (idxv == j || bit)) ? 1 : 0;
            pos -= dec;
        }
        if (lane < steps) tst[j_hi - lane] = acc;
    }
}

// ---------------- small t-indexed outputs; DUR via binary search over TSTAR ----------------
// TSTAR[b][j] is monotone non-decreasing in j, so
// DUR[t] = lower_bound(t+1) - lower_bound(t)  (exact integer count).
__device__ __forceinline__ int lbound2048(const int* __restrict__ ts, int n, int x)
{
    int pos = 0;
    #pragma unroll
    for (int step = 2048; step >= 1; step >>= 1) {
        int np = pos + step;
        if (np <= n && ts[np - 1] < x) pos = np;
    }
    return pos;
}

__global__ __launch_bounds__(256) void k_small(
    const float* __restrict__ odur, const int* __restrict__ xlp,
    const int* __restrict__ ylp, const int* __restrict__ TSTAR,
    float* __restrict__ out4, float* __restrict__ out5)
{
    int gid = blockIdx.x * 256 + threadIdx.x;
    int b = gid >> 9, t = gid & 511;
    out4[gid] = odur[gid];
    int xlen = xlp[b];
    int ylen = (ylp[b] >> 1) << 1;
    const int* ts = TSTAR + b * TYY;
    float r = 0.0f;
    if (t < xlen) {
        int lo = lbound2048(ts, ylen, t);
        int hi = lbound2048(ts, ylen, t + 1);
        r = log1pf((float)(hi - lo));
    }
    out5[gid] = r;
}

// ---------------- z transpose + gathers (out0, out1, out2) ----------------
__global__ __launch_bounds__(256) void k_out_sc(
    const float* __restrict__ z, const float* __restrict__ OMTf,
    const float* __restrict__ OLSTf, const int* __restrict__ TSTAR,
    const int* __restrict__ ylp,
    float* __restrict__ out0, float* __restrict__ out1,
    float* __restrict__ out2)
{
    int b = blockIdx.y;
    int s0 = blockIdx.x * 32;
    int tid = threadIdx.x;
    int ylen = (ylp[b] >> 1) << 1;
    __shared__ int sT[32];
    __shared__ float zt[32][81];
    if (tid < 32) {
        int s = s0 + tid;
        sT[tid] = (s < ylen) ? TSTAR[b * TYY + s] : 0;
    }
    int c_l = tid >> 5, s_l = tid & 31;
    #pragma unroll
    for (int cp = 0; cp < 10; ++cp) {
        int c = cp * 8 + c_l;
        zt[s_l][c] = z[((size_t)b * CC + c) * TYY + s0 + s_l];
    }
    __syncthreads();
    for (int e = tid; e < 32 * 80; e += 256) {
        int sl = e / 80;
        int cc = e - sl * 80;
        int s = s0 + sl;
        bool valid = s < ylen;
        int t = sT[sl];
        size_t o = ((size_t)b * TYY + s) * 80 + cc;
        size_t g = ((size_t)b * TXX + t) * 80 + cc;
        out0[o] = valid ? zt[sl][cc] : 0.0f;
        out1[o] = valid ? OMTf[g]    : 0.0f;
        out2[o] = valid ? OLSTf[g]   : 0.0f;
    }
}

// ---------------- alignments (out3), one-hot rows ----------------
__global__ __launch_bounds__(256) void k_attn(
    const int* __restrict__ TSTAR, const int* __restrict__ ylp,
    float* __restrict__ out3)
{
    int b = blockIdx.y;
    int s0 = blockIdx.x * 16;
    int tid = threadIdx.x;
    int ylen = (ylp[b] >> 1) << 1;
    #pragma unroll
    for (int r = 0; r < 16; ++r) {
        int s = s0 + r;
        int tr = (s < ylen) ? TSTAR[b * TYY + s] : -1;
        int t = tid << 1;
        float2 val;
        val.x = (t == tr) ? 1.0f : 0.0f;
        val.y = (t + 1 == tr) ? 1.0f : 0.0f;
        ((float2*)(out3 + ((size_t)b * TYY + s) * TXX))[tid] = val;
    }
}

extern "C" void kernel_launch(void* const* d_in, const int* in_sizes, int n_in,
                              void* d_out, int out_size, void* d_ws, size_t ws_size,
                              hipStream_t stream)
{
    const float* om   = (const float*)d_in[0];
    const float* ols  = (const float*)d_in[1];
    const float* odur = (const float*)d_in[2];
    const float* z    = (const float*)d_in[3];
    const int* xl = (const int*)d_in[4];
    const int* yl = (const int*)d_in[5];

    float* out0 = (float*)d_out;            // [B,Ty,C]  5,242,880 f32
    float* out1 = out0 + 5242880;           // [B,Ty,C]
    float* out2 = out0 + 10485760;          // [B,Ty,C]
    float* out3 = out0 + 15728640;          // [B,Ty,Tx] 33,554,432 f32
    float* out4 = out0 + 49283072;          // [B,Tx,1]
    float* out5 = out0 + 49299456;          // [B,Tx,1]

    // Scratch aliased into d_out (stream-ordered: consumers finish before overwrite):
    float* SA   = out0;                     // out0 region; k_out_sc overwrites after k_logp
    float* SB   = out0 + 1310720;
    float* logp = out3;                     // exactly out3's region; k_attn overwrites last

    // Workspace (15,138,816 B total)
    char* ws = (char*)d_ws;
    float* L1 = (float*)ws;                                  // 65,536 B
    float* L4 = (float*)(ws + 65536);                        // 65,536 B
    float* OMTf  = (float*)(ws + 131072);                    // 5,242,880 B
    float* OLSTf = (float*)(ws + 5373952);                   // 5,242,880 B
    unsigned long long* BITS64 = (unsigned long long*)(ws + 10616832); // 4,194,304 B
    int* TSTAR = (int*)(ws + 14811136);                      // 262,144 B

    hipLaunchKernelGGL(k_prep, dim3(8, 32), dim3(256), 0, stream,
                       om, ols, SA, SB, L1, L4, OMTf, OLSTf);
    hipLaunchKernelGGL(k_logp, dim3(8, 16, 32), dim3(256), 0, stream,
                       SA, SB, L1, L4, z, xl, yl, logp);
    hipLaunchKernelGGL(k_fwd, dim3(32), dim3(512), 0, stream, logp, yl, BITS64);
    hipLaunchKernelGGL(k_bwd, dim3(32), dim3(64), 0, stream, BITS64, xl, yl, TSTAR);
    hipLaunchKernelGGL(k_small, dim3(64), dim3(256), 0, stream, odur, xl, yl, TSTAR, out4, out5);
    hipLaunchKernelGGL(k_out_sc, dim3(64, 32), dim3(256), 0, stream,
                       z, OMTf, OLSTf, TSTAR, yl, out0, out1, out2);
    hipLaunchKernelGGL(k_attn, dim3(128, 32), dim3(256), 0, stream, TSTAR, yl, out3);
}

// Round 3
// 646.061 us; speedup vs baseline: 1.1505x; 1.0358x over previous
//
#include <hip/hip_runtime.h>
#include <math.h>

#define BB  32
#define CC  80
#define TXX 512
#define TYY 2048
#define NEGV -1e9f

typedef float v2f __attribute__((ext_vector_type(2)));

// ---------------- prep: o_scale tables, per-t terms, f32 transposed copies ----------------
__global__ __launch_bounds__(256) void k_prep(
    const float* __restrict__ om, const float* __restrict__ ols,
    float* __restrict__ SA, float* __restrict__ SB,
    float* __restrict__ L1, float* __restrict__ L4,
    float* __restrict__ OMTf, float* __restrict__ OLSTf)
{
    int b = blockIdx.y;
    int t0 = blockIdx.x * 64;
    int tid = threadIdx.x;
    int cl = tid >> 6;          // 0..3
    int tl = tid & 63;
    __shared__ float sm[64][81], sl[64][81], ssa[64][81];
    #pragma unroll
    for (int cp = 0; cp < 20; ++cp) {
        int c = cp * 4 + cl;
        size_t gidx = ((size_t)b * CC + c) * TXX + t0 + tl;
        float m = om[gidx], ls = ols[gidx];
        float sa = expf(-2.0f * ls);
        SA[gidx] = sa;
        SB[gidx] = m * sa;
        sm[tl][c] = m; sl[tl][c] = ls; ssa[tl][c] = sa;
    }
    __syncthreads();
    if (tid < 64) {
        float l1 = 0.f, l4 = 0.f;
        #pragma unroll 4
        for (int c = 0; c < CC; ++c) {
            float m = sm[tid][c], ls = sl[tid][c], sa = ssa[tid][c];
            l1 += (-0.9189385332046727f - ls);
            l4 += ((-0.5f * m) * m) * sa;
        }
        int g = b * TXX + t0 + tid;
        L1[g] = l1; L4[g] = l4;
    }
    size_t obase = (size_t)b * TXX * CC + (size_t)t0 * CC;
    for (int e = tid; e < 64 * CC; e += 256) {
        int t = e / CC, c = e - t * CC;
        OMTf[obase + e]  = sm[t][c];
        OLSTf[obase + e] = sl[t][c];
    }
}

// ---------------- logp GEMM: [Tx,K=80]x[K,Ty] per batch, packed-f32 vector ----------------
__global__ __launch_bounds__(256) void k_logp(
    const float* __restrict__ SA, const float* __restrict__ SB,
    const float* __restrict__ L1, const float* __restrict__ L4,
    const float* __restrict__ z,
    const int* __restrict__ xlp, const int* __restrict__ ylp,
    float* __restrict__ logp)
{
    int b = blockIdx.z;
    int ylen = (ylp[b] >> 1) << 1;
    int s0 = blockIdx.y * 128;
    if (s0 >= ylen) return;            // DP never reads rows >= ylen; k_attn overwrites later
    int t0 = blockIdx.x * 64;
    int xlen = xlp[b];
    int tid = threadIdx.x;

    __shared__ float sA[16][64], sB[16][64], sZ[16][128], sW[16][128];

    v2f acc2[4][4], acc3[4][4];
    #pragma unroll
    for (int i = 0; i < 4; ++i)
        #pragma unroll
        for (int p = 0; p < 4; ++p) { acc2[i][p] = (v2f){0.f, 0.f}; acc3[i][p] = (v2f){0.f, 0.f}; }

    int tt = (tid & 15) << 2;
    int ss = (tid >> 4) << 3;
    int r  = tid >> 4;
    int c4 = (tid & 15) << 2;
    int s8 = (tid & 15) << 3;

    for (int c0 = 0; c0 < CC; c0 += 16) {
        const float* pa = SA + ((size_t)b * CC + (c0 + r)) * TXX + t0 + c4;
        const float* pb = SB + ((size_t)b * CC + (c0 + r)) * TXX + t0 + c4;
        float4 va = *(const float4*)pa;
        float4 vb = *(const float4*)pb;
        *(float4*)&sA[r][c4] = va;
        *(float4*)&sB[r][c4] = vb;

        const float* pz = z + ((size_t)b * CC + (c0 + r)) * TYY + s0 + s8;
        float4 q0 = *(const float4*)pz;
        float4 q1 = *(const float4*)(pz + 4);
        float zf[8] = {q0.x, q0.y, q0.z, q0.w, q1.x, q1.y, q1.z, q1.w};
        #pragma unroll
        for (int i = 0; i < 8; ++i) {
            sZ[r][s8 + i] = zf[i];
            sW[r][s8 + i] = (-0.5f * zf[i]) * zf[i];
        }
        __syncthreads();
        #pragma unroll
        for (int kc = 0; kc < 16; ++kc) {
            float4 a2 = *(const float4*)&sA[kc][tt];
            float4 a3 = *(const float4*)&sB[kc][tt];
            const v2f* zp = (const v2f*)&sZ[kc][ss];
            const v2f* wp = (const v2f*)&sW[kc][ss];
            v2f bz[4] = {zp[0], zp[1], zp[2], zp[3]};
            v2f bw[4] = {wp[0], wp[1], wp[2], wp[3]};
            float av2[4] = {a2.x, a2.y, a2.z, a2.w};
            float av3[4] = {a3.x, a3.y, a3.z, a3.w};
            #pragma unroll
            for (int i = 0; i < 4; ++i) {
                v2f d2 = {av2[i], av2[i]};
                v2f d3 = {av3[i], av3[i]};
                #pragma unroll
                for (int p = 0; p < 4; ++p) {
                    acc2[i][p] = __builtin_elementwise_fma(d2, bw[p], acc2[i][p]);
                    acc3[i][p] = __builtin_elementwise_fma(d3, bz[p], acc3[i][p]);
                }
            }
        }
        __syncthreads();
    }

    float l1a[4], l4a[4]; int bad[4];
    #pragma unroll
    for (int i = 0; i < 4; ++i) {
        int t = t0 + tt + i;
        l1a[i] = L1[b * TXX + t];
        l4a[i] = L4[b * TXX + t];
        bad[i] = (t >= xlen);
    }
    #pragma unroll
    for (int p = 0; p < 4; ++p) {
        #pragma unroll
        for (int h = 0; h < 2; ++h) {
            int s = s0 + ss + 2 * p + h;
            float vals[4];
            #pragma unroll
            for (int i = 0; i < 4; ++i) {
                float a2v = h ? acc2[i][p].y : acc2[i][p].x;
                float a3v = h ? acc3[i][p].y : acc3[i][p].x;
                float v = ((l1a[i] + a2v) + a3v) + l4a[i];
                vals[i] = bad[i] ? NEGV : v;
            }
            float4 o; o.x = vals[0]; o.y = vals[1]; o.z = vals[2]; o.w = vals[3];
            *(float4*)&logp[((size_t)b * TYY + s) * TXX + t0 + tt] = o;
        }
    }
}

// ---------------- forward Viterbi DP: skewed 8-wave pipeline, 1 col per lane ----------------
// Round r: wave w runs s-block blk=r-w (64 steps). Boundary v[64w-1] flows
// wave(w-1)->wave(w) via per-round register latch + 1 LDS ring write/read.
// Step body is branch-free -> full unroll.
// Lane shift uses DPP wave_shr:1 (update_dpp, old=boundary) instead of
// __shfl_up's ds_bpermute: removes the LDS round-trip + lane0 cndmask from
// the serial chain (187 cyc/step -> target ~60-90).
__global__ __launch_bounds__(512) void k_fwd(
    const float* __restrict__ logp, const int* __restrict__ ylp,
    unsigned long long* __restrict__ BITS64)   // [b][8][2048]
{
    int b = blockIdx.x;
    int tid = threadIdx.x;
    int w = tid >> 6, lane = tid & 63;
    int n = (ylp[b] >> 1) << 1;          // 1024..2048, even
    int nm1 = n - 1;
    int nb = (n + 63) >> 6;
    const float* lpt = logp + (size_t)b * TYY * TXX + tid;   // column t=tid
    unsigned long long* bout = BITS64 + ((size_t)b * 8 + w) * TYY;

    __shared__ float bnd[8][4][64];      // [wave][ring][step-in-block] latch of v63

    float v = (tid == 0) ? 0.0f : NEGV;
    float c[16];
    unsigned blo = 0u, bhi = 0u;
    int rounds = nb + 7;
    for (int r = 0; r < rounds; ++r) {
        int blk = r - w;
        if (blk >= 0 && blk < nb) {
            int S0 = blk << 6;
            if (blk == 0) {              // fill prefetch pipe (rows 0..15 valid: n>=1024)
                #pragma unroll
                for (int i = 0; i < 16; ++i) c[i] = lpt[(size_t)i * TXX];
            }
            // BL[lane] = v63 after step S0-1+lane (from wave w-1's latches)
            float BL;
            if (w == 0) {
                BL = NEGV;
            } else {
                const float* srcp = (lane == 0) ? &bnd[w - 1][(blk + 3) & 3][63]
                                                : &bnd[w - 1][blk & 3][lane - 1];
                BL = *srcp;
                if (blk == 0 && lane == 0) BL = NEGV;   // step -1 boundary
            }
            float BLout = 0.0f;
            #pragma unroll
            for (int j = 0; j < 64; ++j) {
                float cc = c[j & 15];
                int ps = S0 + j + 16; ps = (ps > nm1) ? nm1 : ps;   // scalar clamp, no branch
                c[j & 15] = lpt[(size_t)ps * TXX];
                // boundary value for this step (wave-uniform scalar)
                int blj = (int)__builtin_amdgcn_readlane(__float_as_uint(BL), j);
                // left[lane] = v[lane-1]; lane0 gets blj (old operand, bound_ctrl=0)
                float left = __uint_as_float((unsigned)__builtin_amdgcn_update_dpp(
                    blj, (int)__float_as_uint(v), 0x138 /*wave_shr:1*/, 0xf, 0xf, false));
                unsigned long long m = __ballot(v < left);   // bits of row S0+j-1
                bool me = (lane == j);
                blo = me ? (unsigned)m : blo;
                bhi = me ? (unsigned)(m >> 32) : bhi;
                v = cc + fmaxf(v, left);
                float v63 = __uint_as_float(
                    __builtin_amdgcn_readlane(__float_as_uint(v), 63));
                BLout = me ? v63 : BLout;
            }
            bnd[w][blk & 3][lane] = BLout;
            int row = S0 - 1 + lane;
            if (row >= 0 && S0 + lane < n)
                bout[row] = (((unsigned long long)bhi) << 32) | blo;
        }
        __syncthreads();
    }
}

// ---------------- backtrack: wave-uniform SALU chain over u64 bit planes ----------------
// All 64 lanes share the same idx chain (wave-uniform) -> broadcast via v_readlane
// (compile-time lane index, no LDS on the critical path); decision arithmetic stays
// in uniform scalar ops. 64-step chunks; each lane holds one row's 128-bit window
// (2 coalesced u64 loads per chunk). tstar captured via per-lane cndmask side chain.
// No atomics: DUR is recovered in k_small by binary search over monotone TSTAR.
__global__ __launch_bounds__(64) void k_bwd(
    const unsigned long long* __restrict__ BITS64, const int* __restrict__ xlp,
    const int* __restrict__ ylp, int* __restrict__ TSTAR)
{
    int b = blockIdx.x, lane = threadIdx.x;
    int ylen = (ylp[b] >> 1) << 1;       // >= 1024, even
    int xlen = xlp[b];
    const unsigned long long* bb = BITS64 + (size_t)b * 8 * TYY;
    int* tst = TSTAR + b * TYY;

    int idx = xlen - 1;                  // wave-uniform
    int j_hi = ylen - 1;

    // full 64-step chunks
    while (j_hi >= 63) {
        int e = idx >> 6;
        int base_w = (e > 0) ? (e - 1) : 0;      // window planes {base_w, base_w+1}, base_w<=6
        int base_bit = base_w << 6;              // pos = idx-base_bit in [0,127], stays >=0
        int row = j_hi - 1 - lane;               // row consumed at step k==lane
        unsigned long long wl = 0ull, wh = 0ull;
        if (row >= 0) {
            wl = bb[(size_t)base_w * TYY + row];
            wh = bb[(size_t)(base_w + 1) * TYY + row];
        }
        unsigned wl0 = (unsigned)wl, wl1 = (unsigned)(wl >> 32);
        unsigned wh0 = (unsigned)wh, wh1 = (unsigned)(wh >> 32);
        int acc = 0;
        int pos = idx - base_bit;
        #pragma unroll
        for (int k = 0; k < 64; ++k) {
            int j = j_hi - k;
            unsigned a0 = __builtin_amdgcn_readlane(wl0, k);   // off the idx chain
            unsigned a1 = __builtin_amdgcn_readlane(wl1, k);
            unsigned c0 = __builtin_amdgcn_readlane(wh0, k);
            unsigned c1 = __builtin_amdgcn_readlane(wh1, k);
            unsigned long long wkl = ((unsigned long long)a1 << 32) | a0;
            unsigned long long wkh = ((unsigned long long)c1 << 32) | c0;
            unsigned long long sel = (pos & 64) ? wkh : wkl;
            unsigned bit = (unsigned)(sel >> (pos & 63)) & 1u;
            int idxv = pos + base_bit;
            acc = (lane == k) ? idxv : acc;                    // tstar[j] side chain
            int dec = (idxv != 0 && j > 0 && (idxv == j || bit)) ? 1 : 0;
            pos -= dec;
        }
        idx = pos + base_bit;
        tst[j_hi - lane] = acc;                  // lane k holds tstar[j_hi-k]
        j_hi -= 64;
    }
    // tail chunk (<= 63 steps)
    if (j_hi >= 0) {
        int steps = j_hi + 1;
        int e = idx >> 6;
        int base_w = (e > 0) ? (e - 1) : 0;
        int base_bit = base_w << 6;
        int row = j_hi - 1 - lane;
        unsigned long long wl = 0ull, wh = 0ull;
        if (row >= 0) {
            wl = bb[(size_t)base_w * TYY + row];
            wh = bb[(size_t)(base_w + 1) * TYY + row];
        }
        unsigned wl0 = (unsigned)wl, wl1 = (unsigned)(wl >> 32);
        unsigned wh0 = (unsigned)wh, wh1 = (unsigned)(wh >> 32);
        int acc = 0;
        int pos = idx - base_bit;
        for (int k = 0; k < steps; ++k) {
            int j = j_hi - k;
            unsigned a0 = __builtin_amdgcn_readlane(wl0, k);
            unsigned a1 = __builtin_amdgcn_readlane(wl1, k);
            unsigned c0 = __builtin_amdgcn_readlane(wh0, k);
            unsigned c1 = __builtin_amdgcn_readlane(wh1, k);
            unsigned long long wkl = ((unsigned long long)a1 << 32) | a0;
            unsigned long long wkh = ((unsigned long long)c1 << 32) | c0;
            unsigned long long sel = (pos & 64) ? wkh : wkl;
            unsigned bit = (unsigned)(sel >> (pos & 63)) & 1u;
            int idxv = pos + base_bit;
            acc = (lane == k) ? idxv : acc;
            int dec = (idxv != 0 && j > 0 && (idxv == j || bit)) ? 1 : 0;
            pos -= dec;
        }
        if (lane < steps) tst[j_hi - lane] = acc;
    }
}

// ---------------- small t-indexed outputs; DUR via binary search over TSTAR ----------------
// TSTAR[b][j] is monotone non-decreasing in j, so
// DUR[t] = lower_bound(t+1) - lower_bound(t)  (exact integer count).
__device__ __forceinline__ int lbound2048(const int* __restrict__ ts, int n, int x)
{
    int pos = 0;
    #pragma unroll
    for (int step = 2048; step >= 1; step >>= 1) {
        int np = pos + step;
        if (np <= n && ts[np - 1] < x) pos = np;
    }
    return pos;
}

__global__ __launch_bounds__(256) void k_small(
    const float* __restrict__ odur, const int* __restrict__ xlp,
    const int* __restrict__ ylp, const int* __restrict__ TSTAR,
    float* __restrict__ out4, float* __restrict__ out5)
{
    int gid = blockIdx.x * 256 + threadIdx.x;
    int b = gid >> 9, t = gid & 511;
    out4[gid] = odur[gid];
    int xlen = xlp[b];
    int ylen = (ylp[b] >> 1) << 1;
    const int* ts = TSTAR + b * TYY;
    float r = 0.0f;
    if (t < xlen) {
        int lo = lbound2048(ts, ylen, t);
        int hi = lbound2048(ts, ylen, t + 1);
        r = log1pf((float)(hi - lo));
    }
    out5[gid] = r;
}

// ---------------- z transpose + gathers (out0, out1, out2) ----------------
__global__ __launch_bounds__(256) void k_out_sc(
    const float* __restrict__ z, const float* __restrict__ OMTf,
    const float* __restrict__ OLSTf, const int* __restrict__ TSTAR,
    const int* __restrict__ ylp,
    float* __restrict__ out0, float* __restrict__ out1,
    float* __restrict__ out2)
{
    int b = blockIdx.y;
    int s0 = blockIdx.x * 32;
    int tid = threadIdx.x;
    int ylen = (ylp[b] >> 1) << 1;
    __shared__ int sT[32];
    __shared__ float zt[32][81];
    if (tid < 32) {
        int s = s0 + tid;
        sT[tid] = (s < ylen) ? TSTAR[b * TYY + s] : 0;
    }
    int c_l = tid >> 5, s_l = tid & 31;
    #pragma unroll
    for (int cp = 0; cp < 10; ++cp) {
        int c = cp * 8 + c_l;
        zt[s_l][c] = z[((size_t)b * CC + c) * TYY + s0 + s_l];
    }
    __syncthreads();
    for (int e = tid; e < 32 * 80; e += 256) {
        int sl = e / 80;
        int cc = e - sl * 80;
        int s = s0 + sl;
        bool valid = s < ylen;
        int t = sT[sl];
        size_t o = ((size_t)b * TYY + s) * 80 + cc;
        size_t g = ((size_t)b * TXX + t) * 80 + cc;
        out0[o] = valid ? zt[sl][cc] : 0.0f;
        out1[o] = valid ? OMTf[g]    : 0.0f;
        out2[o] = valid ? OLSTf[g]   : 0.0f;
    }
}

// ---------------- alignments (out3), one-hot rows ----------------
__global__ __launch_bounds__(256) void k_attn(
    const int* __restrict__ TSTAR, const int* __restrict__ ylp,
    float* __restrict__ out3)
{
    int b = blockIdx.y;
    int s0 = blockIdx.x * 16;
    int tid = threadIdx.x;
    int ylen = (ylp[b] >> 1) << 1;
    #pragma unroll
    for (int r = 0; r < 16; ++r) {
        int s = s0 + r;
        int tr = (s < ylen) ? TSTAR[b * TYY + s] : -1;
        int t = tid << 1;
        float2 val;
        val.x = (t == tr) ? 1.0f : 0.0f;
        val.y = (t + 1 == tr) ? 1.0f : 0.0f;
        ((float2*)(out3 + ((size_t)b * TYY + s) * TXX))[tid] = val;
    }
}

extern "C" void kernel_launch(void* const* d_in, const int* in_sizes, int n_in,
                              void* d_out, int out_size, void* d_ws, size_t ws_size,
                              hipStream_t stream)
{
    const float* om   = (const float*)d_in[0];
    const float* ols  = (const float*)d_in[1];
    const float* odur = (const float*)d_in[2];
    const float* z    = (const float*)d_in[3];
    const int* xl = (const int*)d_in[4];
    const int* yl = (const int*)d_in[5];

    float* out0 = (float*)d_out;            // [B,Ty,C]  5,242,880 f32
    float* out1 = out0 + 5242880;           // [B,Ty,C]
    float* out2 = out0 + 10485760;          // [B,Ty,C]
    float* out3 = out0 + 15728640;          // [B,Ty,Tx] 33,554,432 f32
    float* out4 = out0 + 49283072;          // [B,Tx,1]
    float* out5 = out0 + 49299456;          // [B,Tx,1]

    // Scratch aliased into d_out (stream-ordered: consumers finish before overwrite):
    float* SA   = out0;                     // out0 region; k_out_sc overwrites after k_logp
    float* SB   = out0 + 1310720;
    float* logp = out3;                     // exactly out3's region; k_attn overwrites last

    // Workspace (15,138,816 B total)
    char* ws = (char*)d_ws;
    float* L1 = (float*)ws;                                  // 65,536 B
    float* L4 = (float*)(ws + 65536);                        // 65,536 B
    float* OMTf  = (float*)(ws + 131072);                    // 5,242,880 B
    float* OLSTf = (float*)(ws + 5373952);                   // 5,242,880 B
    unsigned long long* BITS64 = (unsigned long long*)(ws + 10616832); // 4,194,304 B
    int* TSTAR = (int*)(ws + 14811136);                      // 262,144 B

    hipLaunchKernelGGL(k_prep, dim3(8, 32), dim3(256), 0, stream,
                       om, ols, SA, SB, L1, L4, OMTf, OLSTf);
    hipLaunchKernelGGL(k_logp, dim3(8, 16, 32), dim3(256), 0, stream,
                       SA, SB, L1, L4, z, xl, yl, logp);
    hipLaunchKernelGGL(k_fwd, dim3(32), dim3(512), 0, stream, logp, yl, BITS64);
    hipLaunchKernelGGL(k_bwd, dim3(32), dim3(64), 0, stream, BITS64, xl, yl, TSTAR);
    hipLaunchKernelGGL(k_small, dim3(64), dim3(256), 0, stream, odur, xl, yl, TSTAR, out4, out5);
    hipLaunchKernelGGL(k_out_sc, dim3(64, 32), dim3(256), 0, stream,
                       z, OMTf, OLSTf, TSTAR, yl, out0, out1, out2);
    hipLaunchKernelGGL(k_attn, dim3(128, 32), dim3(256), 0, stream, TSTAR, yl, out3);
}